// Round 1
// baseline (449.908 us; speedup 1.0000x reference)
//
#include <hip/hip_runtime.h>

typedef __bf16 bf16;
typedef __bf16 bf16x8_t __attribute__((ext_vector_type(8)));
typedef __bf16 bf16x4_t __attribute__((ext_vector_type(4)));
typedef float f32x4_t __attribute__((ext_vector_type(4)));

#define S_ 2048
#define E_ 1024
#define HD 64

// ---------- fp32 -> bf16 convert (x) ----------
__global__ void cvt4(const float* __restrict__ in, bf16* __restrict__ out) {
  int i = (blockIdx.x * 256 + threadIdx.x) * 4;
  float4 v = *(const float4*)(in + i);
  bf16x4_t o = { (bf16)v.x, (bf16)v.y, (bf16)v.z, (bf16)v.w };
  *(bf16x4_t*)(out + i) = o;
}

// ---------- fp32 [R][C] -> bf16 [C][R] (weights) ----------
__global__ void transpose_cvt(const float* __restrict__ in, bf16* __restrict__ out,
                              int R, int C) {
  __shared__ float tile[32][33];
  int c0 = blockIdx.x * 32, r0 = blockIdx.y * 32;
  int tx = threadIdx.x & 31, ty = threadIdx.x >> 5;
#pragma unroll
  for (int i = 0; i < 32; i += 8)
    tile[ty + i][tx] = in[(size_t)(r0 + ty + i) * C + c0 + tx];
  __syncthreads();
#pragma unroll
  for (int i = 0; i < 32; i += 8)
    out[(size_t)(c0 + ty + i) * R + r0 + tx] = (bf16)tile[tx][ty + i];
}

// ---------- V [BH][S][64] -> Vt [BH][64][S] ----------
__global__ void transpose_v(const bf16* __restrict__ V, bf16* __restrict__ Vt) {
  __shared__ bf16 t[64][66];  // +2 pad: 2-way bank alias only (free per m136)
  int s0 = blockIdx.x * 64, bh = blockIdx.y;
  const bf16* src = V + ((size_t)bh * S_ + s0) * HD;
#pragma unroll
  for (int c = 0; c < 16; c++) {
    int idx = c * 256 + threadIdx.x;       // [s][d], d fastest -> coalesced read
    t[idx & 63][idx >> 6] = src[idx];
  }
  __syncthreads();
  bf16* dst = Vt + (size_t)bh * HD * S_ + s0;
#pragma unroll
  for (int c = 0; c < 16; c++) {
    int idx = c * 256 + threadIdx.x;       // [d][s], s fastest -> coalesced write
    int d = idx >> 6, s = idx & 63;
    dst[(size_t)d * S_ + s] = t[d][s];
  }
}

// ---------- QKV GEMM: C[m,n] = A[m,:]·Bt[n,:] + bias[n]; scatter to Q/K/V ----------
// A [8192][1024] bf16, Bt [3072][1024] bf16. 128x128 tile, 4 waves of 64x64, BK=32.
__global__ __launch_bounds__(256, 2)
void gemm_qkv(const bf16* __restrict__ A, const bf16* __restrict__ Bt,
              const float* __restrict__ bias,
              bf16* __restrict__ Q, bf16* __restrict__ K, bf16* __restrict__ V) {
  __shared__ bf16 As[128 * 32];
  __shared__ bf16 Bs[128 * 32];
  const int tid = threadIdx.x;
  const int wave = tid >> 6, lane = tid & 63;
  const int quad = lane >> 4, l16 = lane & 15;
  const int wm = wave >> 1, wn = wave & 1;
  const int bm = blockIdx.x, bn = blockIdx.y;
  const int Kd = 1024;

  f32x4_t acc[4][4];
#pragma unroll
  for (int i = 0; i < 4; i++)
#pragma unroll
    for (int j = 0; j < 4; j++) acc[i][j] = (f32x4_t){0.f, 0.f, 0.f, 0.f};

  const int arow = tid >> 1, akoff = (tid & 1) * 16;
  const bf16* Ag = A + (size_t)(bm * 128 + arow) * Kd + akoff;
  const bf16* Bg = Bt + (size_t)(bn * 128 + arow) * Kd + akoff;
  bf16* AsW = &As[arow * 32 + akoff];
  bf16* BsW = &Bs[arow * 32 + akoff];

  for (int k0 = 0; k0 < Kd; k0 += 32) {
    bf16x8_t a0 = *(const bf16x8_t*)(Ag + k0);
    bf16x8_t a1 = *(const bf16x8_t*)(Ag + k0 + 8);
    bf16x8_t b0 = *(const bf16x8_t*)(Bg + k0);
    bf16x8_t b1 = *(const bf16x8_t*)(Bg + k0 + 8);
    __syncthreads();
    *(bf16x8_t*)AsW = a0; *(bf16x8_t*)(AsW + 8) = a1;
    *(bf16x8_t*)BsW = b0; *(bf16x8_t*)(BsW + 8) = b1;
    __syncthreads();
    bf16x8_t af[4], bfr[4];
#pragma unroll
    for (int i = 0; i < 4; i++)
      af[i] = *(const bf16x8_t*)&As[(wm * 64 + i * 16 + l16) * 32 + quad * 8];
#pragma unroll
    for (int j = 0; j < 4; j++)
      bfr[j] = *(const bf16x8_t*)&Bs[(wn * 64 + j * 16 + l16) * 32 + quad * 8];
#pragma unroll
    for (int i = 0; i < 4; i++)
#pragma unroll
      for (int j = 0; j < 4; j++)
        acc[i][j] = __builtin_amdgcn_mfma_f32_16x16x32_bf16(af[i], bfr[j], acc[i][j], 0, 0, 0);
  }

  // epilogue: n decides q/k/v; layout [B,H,S,64]
#pragma unroll
  for (int j = 0; j < 4; j++) {
    int n_g = bn * 128 + wn * 64 + j * 16 + l16;
    float bv = bias[n_g];
    int which = n_g >> 10;
    int c = n_g & 1023;
    int h = c >> 6, d = c & 63;
    bf16* dst = (which == 0) ? Q : (which == 1) ? K : V;
#pragma unroll
    for (int i = 0; i < 4; i++) {
      int m0 = bm * 128 + wm * 64 + i * 16 + quad * 4;
#pragma unroll
      for (int r = 0; r < 4; r++) {
        int m_g = m0 + r;
        int b = m_g >> 11, s = m_g & 2047;
        dst[((size_t)((b * 16 + h) * S_ + s)) * HD + d] = (bf16)(acc[i][j][r] + bv);
      }
    }
  }
}

// ---------- Proj GEMM: out[m,n] = A[m,:]·Bt[n,:] + bias[n], fp32 out ----------
__global__ __launch_bounds__(256, 2)
void gemm_proj(const bf16* __restrict__ A, const bf16* __restrict__ Bt,
               const float* __restrict__ bias, float* __restrict__ out) {
  __shared__ bf16 As[128 * 32];
  __shared__ bf16 Bs[128 * 32];
  const int tid = threadIdx.x;
  const int wave = tid >> 6, lane = tid & 63;
  const int quad = lane >> 4, l16 = lane & 15;
  const int wm = wave >> 1, wn = wave & 1;
  const int bm = blockIdx.x, bn = blockIdx.y;
  const int Kd = 1024;

  f32x4_t acc[4][4];
#pragma unroll
  for (int i = 0; i < 4; i++)
#pragma unroll
    for (int j = 0; j < 4; j++) acc[i][j] = (f32x4_t){0.f, 0.f, 0.f, 0.f};

  const int arow = tid >> 1, akoff = (tid & 1) * 16;
  const bf16* Ag = A + (size_t)(bm * 128 + arow) * Kd + akoff;
  const bf16* Bg = Bt + (size_t)(bn * 128 + arow) * Kd + akoff;
  bf16* AsW = &As[arow * 32 + akoff];
  bf16* BsW = &Bs[arow * 32 + akoff];

  for (int k0 = 0; k0 < Kd; k0 += 32) {
    bf16x8_t a0 = *(const bf16x8_t*)(Ag + k0);
    bf16x8_t a1 = *(const bf16x8_t*)(Ag + k0 + 8);
    bf16x8_t b0 = *(const bf16x8_t*)(Bg + k0);
    bf16x8_t b1 = *(const bf16x8_t*)(Bg + k0 + 8);
    __syncthreads();
    *(bf16x8_t*)AsW = a0; *(bf16x8_t*)(AsW + 8) = a1;
    *(bf16x8_t*)BsW = b0; *(bf16x8_t*)(BsW + 8) = b1;
    __syncthreads();
    bf16x8_t af[4], bfr[4];
#pragma unroll
    for (int i = 0; i < 4; i++)
      af[i] = *(const bf16x8_t*)&As[(wm * 64 + i * 16 + l16) * 32 + quad * 8];
#pragma unroll
    for (int j = 0; j < 4; j++)
      bfr[j] = *(const bf16x8_t*)&Bs[(wn * 64 + j * 16 + l16) * 32 + quad * 8];
#pragma unroll
    for (int i = 0; i < 4; i++)
#pragma unroll
      for (int j = 0; j < 4; j++)
        acc[i][j] = __builtin_amdgcn_mfma_f32_16x16x32_bf16(af[i], bfr[j], acc[i][j], 0, 0, 0);
  }

#pragma unroll
  for (int j = 0; j < 4; j++) {
    int n_g = bn * 128 + wn * 64 + j * 16 + l16;
    float bv = bias[n_g];
#pragma unroll
    for (int i = 0; i < 4; i++) {
      int m0 = bm * 128 + wm * 64 + i * 16 + quad * 4;
#pragma unroll
      for (int r = 0; r < 4; r++)
        out[(size_t)(m0 + r) * 1024 + n_g] = acc[i][j][r] + bv;
    }
  }
}

// ---------- Flash attention (causal). One block per (q-block of 128, bh). ----------
// Wave w owns q-rows [w*32, w*32+32). Q,K: [BH][S][64]; Vt: [BH][64][S].
__global__ __launch_bounds__(256, 1)
void attn_kernel(const bf16* __restrict__ Q, const bf16* __restrict__ K,
                 const bf16* __restrict__ Vt, bf16* __restrict__ O) {
  __shared__ bf16 Ks[128 * 64];   // [s_k][d]    16KB
  __shared__ bf16 Vs[64 * 128];   // [d][s_k]    16KB
  __shared__ bf16 Ps[4][32 * 128];// per-wave P  32KB  (total 64KB)
  const int tid = threadIdx.x;
  const int wave = tid >> 6, lane = tid & 63;
  const int quad = lane >> 4, l16 = lane & 15;
  const int qb = blockIdx.x, bh = blockIdx.y;

  const bf16* Qg = Q + (size_t)bh * S_ * HD;
  const bf16* Kg = K + (size_t)bh * S_ * HD;
  const bf16* Vg = Vt + (size_t)bh * HD * S_;

  // Q fragments (A-layout): m = l16, k = quad*8.. ; 2 row-tiles x 2 k-steps
  bf16x8_t qf[2][2];
#pragma unroll
  for (int i = 0; i < 2; i++)
#pragma unroll
    for (int ks = 0; ks < 2; ks++)
      qf[i][ks] = *(const bf16x8_t*)(Qg + (size_t)(qb * 128 + wave * 32 + i * 16 + l16) * HD
                                     + ks * 32 + quad * 8);

  f32x4_t o[2][4];
#pragma unroll
  for (int i = 0; i < 2; i++)
#pragma unroll
    for (int jd = 0; jd < 4; jd++) o[i][jd] = (f32x4_t){0.f, 0.f, 0.f, 0.f};
  float m_row[2][4], l_row[2][4];
#pragma unroll
  for (int i = 0; i < 2; i++)
#pragma unroll
    for (int r = 0; r < 4; r++) { m_row[i][r] = -1e30f; l_row[i][r] = 0.f; }

  bf16* Pw = &Ps[wave][0];

  for (int kb = 0; kb <= qb; kb++) {
    // stage K (contiguous 16KB) and Vt block (64 rows x 256B) via registers
    const bf16* Ksrc = Kg + (size_t)kb * 128 * HD;
    bf16x8_t kreg[4], vreg[4];
#pragma unroll
    for (int c = 0; c < 4; c++) {
      int f8 = c * 256 + tid;  // 8-element chunk id, 0..1023
      kreg[c] = *(const bf16x8_t*)(Ksrc + (size_t)f8 * 8);
      int vd = f8 >> 4, vs = (f8 & 15) * 8;
      vreg[c] = *(const bf16x8_t*)(Vg + (size_t)vd * S_ + kb * 128 + vs);
    }
    __syncthreads();
#pragma unroll
    for (int c = 0; c < 4; c++) {
      int f8 = c * 256 + tid;
      *(bf16x8_t*)(Ks + f8 * 8) = kreg[c];
      *(bf16x8_t*)(Vs + f8 * 8) = vreg[c];
    }
    __syncthreads();

    // S = Q Kb^T : per wave 32x128 in 2x8 MFMA tiles
    f32x4_t sacc[2][8];
#pragma unroll
    for (int i = 0; i < 2; i++)
#pragma unroll
      for (int j = 0; j < 8; j++) sacc[i][j] = (f32x4_t){0.f, 0.f, 0.f, 0.f};
#pragma unroll
    for (int ks = 0; ks < 2; ks++) {
      bf16x8_t kf[8];
#pragma unroll
      for (int j = 0; j < 8; j++)
        kf[j] = *(const bf16x8_t*)&Ks[(j * 16 + l16) * 64 + ks * 32 + quad * 8];
#pragma unroll
      for (int i = 0; i < 2; i++)
#pragma unroll
        for (int j = 0; j < 8; j++)
          sacc[i][j] = __builtin_amdgcn_mfma_f32_16x16x32_bf16(qf[i][ks], kf[j], sacc[i][j], 0, 0, 0);
    }

    const bool diag = (kb == qb);
#pragma unroll
    for (int i = 0; i < 2; i++) {
      // scale + causal mask (block-local row/col compare; offsets cancel)
#pragma unroll
      for (int j = 0; j < 8; j++)
#pragma unroll
        for (int r = 0; r < 4; r++) {
          float v = sacc[i][j][r] * 0.125f;
          if (diag) {
            int q_row = wave * 32 + i * 16 + quad * 4 + r;
            int k_col = j * 16 + l16;
            if (k_col > q_row) v = -1e30f;
          }
          sacc[i][j][r] = v;
        }
      // online softmax per row (row owned by the 16 lanes of a quad)
#pragma unroll
      for (int r = 0; r < 4; r++) {
        float mx = sacc[i][0][r];
#pragma unroll
        for (int j = 1; j < 8; j++) mx = fmaxf(mx, sacc[i][j][r]);
        mx = fmaxf(mx, __shfl_xor(mx, 1));
        mx = fmaxf(mx, __shfl_xor(mx, 2));
        mx = fmaxf(mx, __shfl_xor(mx, 4));
        mx = fmaxf(mx, __shfl_xor(mx, 8));
        float m_new = fmaxf(m_row[i][r], mx);
        float alpha = __expf(m_row[i][r] - m_new);
        m_row[i][r] = m_new;
        float rs = 0.f;
#pragma unroll
        for (int j = 0; j < 8; j++) {
          float p = __expf(sacc[i][j][r] - m_new);
          sacc[i][j][r] = p;
          rs += p;
        }
        rs += __shfl_xor(rs, 1);
        rs += __shfl_xor(rs, 2);
        rs += __shfl_xor(rs, 4);
        rs += __shfl_xor(rs, 8);
        l_row[i][r] = alpha * l_row[i][r] + rs;
#pragma unroll
        for (int jd = 0; jd < 4; jd++) o[i][jd][r] *= alpha;
      }
      // P: C-layout -> LDS [row][col] (wave-private, no barrier needed)
#pragma unroll
      for (int j = 0; j < 8; j++)
#pragma unroll
        for (int r = 0; r < 4; r++)
          Pw[(i * 16 + quad * 4 + r) * 128 + j * 16 + l16] = (bf16)sacc[i][j][r];
    }

    // O += P Vb : contraction over 128 k-cols, 4 k-steps
#pragma unroll
    for (int ks2 = 0; ks2 < 4; ks2++) {
      bf16x8_t pa[2], vb[4];
#pragma unroll
      for (int i = 0; i < 2; i++)
        pa[i] = *(const bf16x8_t*)&Pw[(i * 16 + l16) * 128 + ks2 * 32 + quad * 8];
#pragma unroll
      for (int jd = 0; jd < 4; jd++)
        vb[jd] = *(const bf16x8_t*)&Vs[(jd * 16 + l16) * 128 + ks2 * 32 + quad * 8];
#pragma unroll
      for (int i = 0; i < 2; i++)
#pragma unroll
        for (int jd = 0; jd < 4; jd++)
          o[i][jd] = __builtin_amdgcn_mfma_f32_16x16x32_bf16(pa[i], vb[jd], o[i][jd], 0, 0, 0);
    }
  }

  // epilogue: O -> [B,S,E] bf16 (token-major for proj GEMM)
  int b = bh >> 4, h = bh & 15;
#pragma unroll
  for (int i = 0; i < 2; i++)
#pragma unroll
    for (int r = 0; r < 4; r++) {
      float inv = 1.0f / l_row[i][r];
      int s_g = qb * 128 + wave * 32 + i * 16 + quad * 4 + r;
      size_t row = (size_t)(b * S_ + s_g) * E_ + h * HD;
#pragma unroll
      for (int jd = 0; jd < 4; jd++)
        O[row + jd * 16 + l16] = (bf16)(o[i][jd][r] * inv);
    }
}

extern "C" void kernel_launch(void* const* d_in, const int* in_sizes, int n_in,
                              void* d_out, int out_size, void* d_ws, size_t ws_size,
                              hipStream_t stream) {
  const float* x      = (const float*)d_in[0];
  const float* W_attn = (const float*)d_in[1];
  const float* b_attn = (const float*)d_in[2];
  const float* W_proj = (const float*)d_in[3];
  const float* b_proj = (const float*)d_in[4];
  float* out = (float*)d_out;

  // workspace layout (bf16 elements); total ~88 MB
  bf16* xb  = (bf16*)d_ws;            // 8192*1024
  bf16* Wat = xb + 8388608ull;        // 3072*1024 (W_attn^T)
  bf16* Wpt = Wat + 3145728ull;       // 1024*1024 (W_proj^T)
  bf16* Qb  = Wpt + 1048576ull;       // [B,H,S,64]
  bf16* Kb  = Qb + 8388608ull;
  bf16* Vb  = Kb + 8388608ull;
  bf16* Vtb = Vb + 8388608ull;        // [B,H,64,S]
  bf16* AOb = xb;                     // alias: x dead after QKV GEMM

  cvt4<<<8192, 256, 0, stream>>>(x, xb);
  transpose_cvt<<<dim3(96, 32), 256, 0, stream>>>(W_attn, Wat, 1024, 3072);
  transpose_cvt<<<dim3(32, 32), 256, 0, stream>>>(W_proj, Wpt, 1024, 1024);
  gemm_qkv<<<dim3(64, 24), 256, 0, stream>>>(xb, Wat, b_attn, Qb, Kb, Vb);
  transpose_v<<<dim3(32, 64), 256, 0, stream>>>(Vb, Vtb);
  attn_kernel<<<dim3(16, 64), 256, 0, stream>>>(Qb, Kb, Vtb, AOb);
  gemm_proj<<<dim3(64, 8), 256, 0, stream>>>(AOb, Wpt, b_proj, out);
}

// Round 2
// 245.266 us; speedup vs baseline: 1.8344x; 1.8344x over previous
//
#include <hip/hip_runtime.h>

typedef __bf16 bf16;
typedef __bf16 bf16x8_t __attribute__((ext_vector_type(8)));
typedef __bf16 bf16x4_t __attribute__((ext_vector_type(4)));
typedef float f32x4_t __attribute__((ext_vector_type(4)));

#define S_ 2048
#define E_ 1024
#define HD 64
#define LOG2E 1.4426950408889634f
#define QSCALE (0.125f * LOG2E)   // 1/sqrt(64) * log2(e), folded into Q

// async global->LDS, 16B per lane; LDS dest is wave-uniform base + lane*16
__device__ __forceinline__ void gl_lds16(const bf16* g, bf16* l) {
  __builtin_amdgcn_global_load_lds(
      (const __attribute__((address_space(1))) unsigned int*)g,
      (__attribute__((address_space(3))) unsigned int*)l, 16, 0, 0);
}

// ---------- fp32 -> bf16 convert (x) ----------
__global__ void cvt4(const float* __restrict__ in, bf16* __restrict__ out) {
  int i = (blockIdx.x * 256 + threadIdx.x) * 4;
  float4 v = *(const float4*)(in + i);
  bf16x4_t o = { (bf16)v.x, (bf16)v.y, (bf16)v.z, (bf16)v.w };
  *(bf16x4_t*)(out + i) = o;
}

// ---------- fp32 [R][C] -> bf16 [C][R] (weights) ----------
__global__ void transpose_cvt(const float* __restrict__ in, bf16* __restrict__ out,
                              int R, int C) {
  __shared__ float tile[32][33];
  int c0 = blockIdx.x * 32, r0 = blockIdx.y * 32;
  int tx = threadIdx.x & 31, ty = threadIdx.x >> 5;
#pragma unroll
  for (int i = 0; i < 32; i += 8)
    tile[ty + i][tx] = in[(size_t)(r0 + ty + i) * C + c0 + tx];
  __syncthreads();
#pragma unroll
  for (int i = 0; i < 32; i += 8)
    out[(size_t)(c0 + ty + i) * R + r0 + tx] = (bf16)tile[tx][ty + i];
}

// ---------- 128x128-tile GEMM, BK=64, global_load_lds staging, XOR-swizzled LDS ----
// MODE 0: QKV epilogue (scatter to Q scaled, K, Vt transposed). MODE 1: proj fp32 out.
template <int MODE>
__global__ __launch_bounds__(256, 2)
void gemm128(const bf16* __restrict__ A, const bf16* __restrict__ Bt,
             const float* __restrict__ bias,
             bf16* __restrict__ Q, bf16* __restrict__ K, bf16* __restrict__ Vt,
             float* __restrict__ Out) {
  __shared__ __align__(16) bf16 As[128 * 64];
  __shared__ __align__(16) bf16 Bs[128 * 64];
  const int tid = threadIdx.x;
  const int wave = tid >> 6, lane = tid & 63;
  const int quad = lane >> 4, l16 = lane & 15;
  const int wm = wave >> 1, wn = wave & 1;
  const int bm = blockIdx.x, bn = blockIdx.y;

  f32x4_t acc[4][4];
#pragma unroll
  for (int i = 0; i < 4; i++)
#pragma unroll
    for (int j = 0; j < 4; j++) acc[i][j] = (f32x4_t){0.f, 0.f, 0.f, 0.f};

  for (int k0 = 0; k0 < 1024; k0 += 64) {
    __syncthreads();
    // stage 16KB A + 16KB B; swizzle source so LDS chunk (row, c) holds
    // global chunk (row, c ^ (row&7)) -> reads are 2-way max
#pragma unroll
    for (int it = 0; it < 4; it++) {
      int id = it * 256 + tid;
      int row = id >> 3, c = id & 7;
      int sc = (c ^ (row & 7)) * 8;
      gl_lds16(A + (size_t)(bm * 128 + row) * 1024 + k0 + sc, As + id * 8);
      gl_lds16(Bt + (size_t)(bn * 128 + row) * 1024 + k0 + sc, Bs + id * 8);
    }
    __syncthreads();
#pragma unroll
    for (int ks = 0; ks < 2; ks++) {
      bf16x8_t af[4], bfr[4];
#pragma unroll
      for (int i = 0; i < 4; i++) {
        int row = wm * 64 + i * 16 + l16;
        af[i] = *(const bf16x8_t*)&As[row * 64 + (((ks * 4 + quad) ^ (row & 7)) * 8)];
      }
#pragma unroll
      for (int j = 0; j < 4; j++) {
        int row = wn * 64 + j * 16 + l16;
        bfr[j] = *(const bf16x8_t*)&Bs[row * 64 + (((ks * 4 + quad) ^ (row & 7)) * 8)];
      }
#pragma unroll
      for (int i = 0; i < 4; i++)
#pragma unroll
        for (int j = 0; j < 4; j++)
          acc[i][j] = __builtin_amdgcn_mfma_f32_16x16x32_bf16(af[i], bfr[j], acc[i][j], 0, 0, 0);
    }
  }

  if (MODE == 0) {
    // n decides q/k/v. Q: [bh][s][64] scaled by QSCALE. K: [bh][s][64]. V: [bh][64][s].
#pragma unroll
    for (int j = 0; j < 4; j++) {
      int n_g = bn * 128 + wn * 64 + j * 16 + l16;
      float bv = bias[n_g];
      int which = n_g >> 10;
      int cc = n_g & 1023;
      int hh = cc >> 6, dd = cc & 63;
#pragma unroll
      for (int i = 0; i < 4; i++) {
        int m0 = bm * 128 + wm * 64 + i * 16 + quad * 4;
        int bb = m0 >> 11, ss0 = m0 & 2047;
        int bhn = bb * 16 + hh;
        if (which == 2) {
          bf16x4_t pk;
#pragma unroll
          for (int r = 0; r < 4; r++) pk[r] = (bf16)(acc[i][j][r] + bv);
          *(bf16x4_t*)&Vt[((size_t)bhn * 64 + dd) * 2048 + ss0] = pk;
        } else {
          bf16* dst = (which == 0) ? Q : K;
          float scl = (which == 0) ? QSCALE : 1.f;
#pragma unroll
          for (int r = 0; r < 4; r++)
            dst[((size_t)bhn * 2048 + ss0 + r) * 64 + dd] = (bf16)((acc[i][j][r] + bv) * scl);
        }
      }
    }
  } else {
#pragma unroll
    for (int j = 0; j < 4; j++) {
      int n_g = bn * 128 + wn * 64 + j * 16 + l16;
      float bv = bias[n_g];
#pragma unroll
      for (int i = 0; i < 4; i++) {
        int m0 = bm * 128 + wm * 64 + i * 16 + quad * 4;
#pragma unroll
        for (int r = 0; r < 4; r++)
          Out[(size_t)(m0 + r) * 1024 + n_g] = acc[i][j][r] + bv;
      }
    }
  }
}

// ---------- Flash attention, S^T formulation ----------
// Block = 256 thr (4 waves); handles q-blocks pid and 15-pid (uniform 17 iters).
// Wave owns 32 q rows. S^T = K·Q^T (m=k-idx, n=q); softmax rows in-lane + 2 shuffles.
// PV: O^T = Vt·P^T. All LDS chunk-XOR-swizzled; K/V staged via global_load_lds.
__global__ __launch_bounds__(256, 2)
void attn_kernel(const bf16* __restrict__ Q, const bf16* __restrict__ K,
                 const bf16* __restrict__ Vt, bf16* __restrict__ O) {
  __shared__ __align__(16) bf16 Ks[128 * 64];    // [k][d]   16KB, 8 chunks/row
  __shared__ __align__(16) bf16 Vs[64 * 128];    // [d][s]   16KB, 16 chunks/row
  __shared__ __align__(16) bf16 Ps[4 * 32 * 128];// per-wave P[q][k] 32KB, 16 chunks/row
  const int tid = threadIdx.x;
  const int wave = tid >> 6, lane = tid & 63;
  const int quad = lane >> 4, l16 = lane & 15;
  const int pid = blockIdx.x, bh = blockIdx.y;
  const int b = bh >> 4, h = bh & 15;

  const bf16* Qg = Q + (size_t)bh * S_ * HD;
  const bf16* Kg = K + (size_t)bh * S_ * HD;
  const bf16* Vg = Vt + (size_t)bh * HD * S_;
  bf16* Pw = Ps + wave * 4096;

  for (int qi = 0; qi < 2; qi++) {
    const int qb = qi ? (15 - pid) : pid;
    // Q fragments (B-operand): n = q row (l16), k = d
    bf16x8_t qf[2][2];
#pragma unroll
    for (int ni = 0; ni < 2; ni++)
#pragma unroll
      for (int ks = 0; ks < 2; ks++)
        qf[ni][ks] = *(const bf16x8_t*)(Qg +
            (size_t)(qb * 128 + wave * 32 + ni * 16 + l16) * HD + ks * 32 + quad * 8);

    f32x4_t o[4][2];
#pragma unroll
    for (int mi = 0; mi < 4; mi++)
#pragma unroll
      for (int ni = 0; ni < 2; ni++) o[mi][ni] = (f32x4_t){0.f, 0.f, 0.f, 0.f};
    float m_[2] = {-1e30f, -1e30f}, l_[2] = {0.f, 0.f};

    for (int kb = 0; kb <= qb; kb++) {
      __syncthreads();  // prior iter's Ks/Vs reads done
      const bf16* Ksrc = Kg + (size_t)kb * 128 * HD;
#pragma unroll
      for (int it = 0; it < 4; it++) {
        int id = it * 256 + tid;
        {
          int row = id >> 3, c = id & 7;
          gl_lds16(Ksrc + row * 64 + ((c ^ (row & 7)) * 8), Ks + id * 8);
        }
        {
          int d = id >> 4, c = id & 15;
          gl_lds16(Vg + (size_t)d * S_ + kb * 128 + ((c ^ (d & 7)) * 8), Vs + id * 8);
        }
      }
      __syncthreads();  // staging complete

      // S^T = K · Q^T : lane holds S^T[k = mi*16+quad*4+r][q = ni*16+l16]
      f32x4_t sacc[8][2];
#pragma unroll
      for (int mi = 0; mi < 8; mi++)
#pragma unroll
        for (int ni = 0; ni < 2; ni++) sacc[mi][ni] = (f32x4_t){0.f, 0.f, 0.f, 0.f};
#pragma unroll
      for (int ks = 0; ks < 2; ks++)
#pragma unroll
        for (int mi = 0; mi < 8; mi++) {
          int kr = mi * 16 + l16;
          bf16x8_t kf = *(const bf16x8_t*)&Ks[kr * 64 + (((ks * 4 + quad) ^ (kr & 7)) * 8)];
          sacc[mi][0] = __builtin_amdgcn_mfma_f32_16x16x32_bf16(kf, qf[0][ks], sacc[mi][0], 0, 0, 0);
          sacc[mi][1] = __builtin_amdgcn_mfma_f32_16x16x32_bf16(kf, qf[1][ks], sacc[mi][1], 0, 0, 0);
        }

      if (kb == qb) {  // causal mask, block-local
#pragma unroll
        for (int mi = 0; mi < 8; mi++)
#pragma unroll
          for (int ni = 0; ni < 2; ni++) {
            int qrow = wave * 32 + ni * 16 + l16;
            int krow = mi * 16 + quad * 4;
#pragma unroll
            for (int r = 0; r < 4; r++)
              if (krow + r > qrow) sacc[mi][ni][r] = -1e30f;
          }
      }

      // online softmax (base-2; scale folded into Q). Stats per q = in-lane + 2 shuffles.
#pragma unroll
      for (int ni = 0; ni < 2; ni++) {
        float mx = sacc[0][ni][0];
#pragma unroll
        for (int mi = 0; mi < 8; mi++)
#pragma unroll
          for (int r = 0; r < 4; r++) mx = fmaxf(mx, sacc[mi][ni][r]);
        mx = fmaxf(mx, __shfl_xor(mx, 16));
        mx = fmaxf(mx, __shfl_xor(mx, 32));
        float mnew = fmaxf(m_[ni], mx);
        float alpha = __builtin_amdgcn_exp2f(m_[ni] - mnew);
        m_[ni] = mnew;
        float rs = 0.f;
#pragma unroll
        for (int mi = 0; mi < 8; mi++)
#pragma unroll
          for (int r = 0; r < 4; r++) {
            float p = __builtin_amdgcn_exp2f(sacc[mi][ni][r] - mnew);
            sacc[mi][ni][r] = p;
            rs += p;
          }
        rs += __shfl_xor(rs, 16);
        rs += __shfl_xor(rs, 32);
        l_[ni] = alpha * l_[ni] + rs;
#pragma unroll
        for (int mi = 0; mi < 4; mi++)
#pragma unroll
          for (int r = 0; r < 4; r++) o[mi][ni][r] *= alpha;
      }

      // P -> wave-private LDS as P[q][k], packed b64, chunk-swizzled
#pragma unroll
      for (int ni = 0; ni < 2; ni++) {
        int qr = ni * 16 + l16;
#pragma unroll
        for (int mi = 0; mi < 8; mi++) {
          bf16x4_t pk;
#pragma unroll
          for (int r = 0; r < 4; r++) pk[r] = (bf16)sacc[mi][ni][r];
          int c = mi * 2 + (quad >> 1);
          *(bf16x4_t*)&Pw[qr * 128 + ((c ^ (qr & 7)) * 8) + (quad & 1) * 4] = pk;
        }
      }

      // O^T += Vt · P^T : lane holds O^T[d = mi*16+quad*4+r][q = ni*16+l16]
#pragma unroll
      for (int ks2 = 0; ks2 < 4; ks2++) {
        bf16x8_t vb[4], pa[2];
#pragma unroll
        for (int mi = 0; mi < 4; mi++) {
          int d = mi * 16 + l16;
          vb[mi] = *(const bf16x8_t*)&Vs[d * 128 + (((ks2 * 4 + quad) ^ (d & 7)) * 8)];
        }
#pragma unroll
        for (int ni = 0; ni < 2; ni++) {
          int qr = ni * 16 + l16;
          pa[ni] = *(const bf16x8_t*)&Pw[qr * 128 + (((ks2 * 4 + quad) ^ (qr & 7)) * 8)];
        }
#pragma unroll
        for (int mi = 0; mi < 4; mi++)
#pragma unroll
          for (int ni = 0; ni < 2; ni++)
            o[mi][ni] = __builtin_amdgcn_mfma_f32_16x16x32_bf16(vb[mi], pa[ni], o[mi][ni], 0, 0, 0);
      }
    }

    // epilogue: O^T lane layout -> O[b][s][h*64+d], packed 4 consecutive d
#pragma unroll
    for (int ni = 0; ni < 2; ni++) {
      float inv = 1.0f / l_[ni];
      int q_g = qb * 128 + wave * 32 + ni * 16 + l16;
      size_t rowb = (size_t)(b * S_ + q_g) * E_ + h * HD;
#pragma unroll
      for (int mi = 0; mi < 4; mi++) {
        bf16x4_t ov;
#pragma unroll
        for (int r = 0; r < 4; r++) ov[r] = (bf16)(o[mi][ni][r] * inv);
        *(bf16x4_t*)&O[rowb + mi * 16 + quad * 4] = ov;
      }
    }
  }
}

extern "C" void kernel_launch(void* const* d_in, const int* in_sizes, int n_in,
                              void* d_out, int out_size, void* d_ws, size_t ws_size,
                              hipStream_t stream) {
  const float* x      = (const float*)d_in[0];
  const float* W_attn = (const float*)d_in[1];
  const float* b_attn = (const float*)d_in[2];
  const float* W_proj = (const float*)d_in[3];
  const float* b_proj = (const float*)d_in[4];
  float* out = (float*)d_out;

  // workspace (bf16 elems), ~75.5 MB total
  bf16* xb  = (bf16*)d_ws;            // 8192*1024
  bf16* Wat = xb + 8388608ull;        // 3072*1024 (W_attn^T)
  bf16* Wpt = Wat + 3145728ull;       // 1024*1024 (W_proj^T)
  bf16* Qb  = Wpt + 1048576ull;       // [B,H,S,64], pre-scaled by QSCALE
  bf16* Kb  = Qb + 8388608ull;        // [B,H,S,64]
  bf16* Vtb = Kb + 8388608ull;        // [B,H,64,S] (written transposed by QKV epilogue)
  bf16* AOb = xb;                     // alias: x dead after QKV GEMM

  cvt4<<<8192, 256, 0, stream>>>(x, xb);
  transpose_cvt<<<dim3(96, 32), 256, 0, stream>>>(W_attn, Wat, 1024, 3072);
  transpose_cvt<<<dim3(32, 32), 256, 0, stream>>>(W_proj, Wpt, 1024, 1024);
  gemm128<0><<<dim3(64, 24), 256, 0, stream>>>(xb, Wat, b_attn, Qb, Kb, Vtb, nullptr);
  attn_kernel<<<dim3(8, 64), 256, 0, stream>>>(Qb, Kb, Vtb, AOb);
  gemm128<1><<<dim3(64, 8), 256, 0, stream>>>(AOb, Wpt, b_proj, nullptr, nullptr, nullptr, out);
}